// Round 5
// baseline (228.804 us; speedup 1.0000x reference)
//
#include <hip/hip_runtime.h>

// y[e] = W2 . relu(W1 . concat(z[src[e]], z[dst[e]]) + b1) + b2
// N=50000, D=128, H=512, E=500000. 131 GFLOP in GEMM1.
// R12: occupancy 2->4 waves/SIMD. R9-R11 plateau (MfmaUtil ~35%) tracks the
// 2-waves/SIMD occupancy forced by breg=128 (64-h W1 slice). Halve the
// slice: 1024-thread block, 16 waves x 32 h. breg 64 + acc 32 (4 e-tiles x
// 2 h-tiles) + transients ~= 124 regs -> launch_bounds(1024,4) -> 16
// waves/CU (~50% occ). LDS-read volume doubles (each wave still reads the
// full A-tile: 512 KB/tile) but LDS and MFMA pipes overlap.
// Schedule reverted to the R10 skeleton (fastest, 150us): 2 barriers/tile,
// gathers issued MID-tile (between kc3/kc4 - balances the LDS write port
// against ds_reads; R11's top-issue collided and regressed), idx loads as
// vmem AFTER gather-issue padding the queue so top-of-tile vmcnt(2)
// retires exactly this tile's 2 gathers. Source-side XOR swizzle
// (slot ^= row&7 within 16-slot half) keeps ds_read_b128 conflict-free.
// SQ_LDS_BANK_CONFLICT ~8M is gather-LDS-write inherent (R10 post-mortem:
// invariant across all layouts) - not addressable from source.

typedef __bf16 bf16x8 __attribute__((ext_vector_type(8)));
typedef float f32x4 __attribute__((ext_vector_type(4)));

__device__ __forceinline__ unsigned short f2b(float f) {
    unsigned int u = __float_as_uint(f);
    u = (u + 0x7fffu + ((u >> 16) & 1u)) >> 16;   // RNE
    return (unsigned short)u;
}

__device__ __forceinline__ void gload_lds16(const unsigned short* g, unsigned short* l) {
    __builtin_amdgcn_global_load_lds(
        (const __attribute__((address_space(1))) unsigned int*)g,
        (__attribute__((address_space(3))) unsigned int*)l, 16, 0, 0);
}

// zb: z as bf16 [N][128].  w1s: W1 swizzled to MFMA fragment order:
// w1s[(hblk*8 + kc)*512 + lane*8 + t] = bf16(W1[hblk*16 + (lane&15)][kc*32 + (lane>>4)*8 + t])
__global__ void prep_kernel(const float* __restrict__ z, const float* __restrict__ W1,
                            unsigned short* __restrict__ zb, unsigned short* __restrict__ w1s,
                            int nz4) {
    int stride = gridDim.x * blockDim.x;
    const int nw = 256 * 64;   // (hblk*8+kc) x lane
    const int total = nz4 + nw;
    for (int idx = blockIdx.x * blockDim.x + threadIdx.x; idx < total; idx += stride) {
        if (idx < nz4) {
            float4 v = ((const float4*)z)[idx];
            ushort4 o;
            o.x = f2b(v.x); o.y = f2b(v.y); o.z = f2b(v.z); o.w = f2b(v.w);
            ((ushort4*)zb)[idx] = o;
        } else {
            int u = idx - nz4;            // 0..16383
            int lane = u & 63;
            int blk  = u >> 6;            // hblk*8 + kc
            int h  = (blk >> 3) * 16 + (lane & 15);
            int kb = (blk & 7) * 32 + (lane >> 4) * 8;
            const float* src = W1 + h * 256 + kb;
            ushort4 o0, o1;
            float4 v0 = *(const float4*)(src);
            float4 v1 = *(const float4*)(src + 4);
            o0.x = f2b(v0.x); o0.y = f2b(v0.y); o0.z = f2b(v0.z); o0.w = f2b(v0.w);
            o1.x = f2b(v1.x); o1.y = f2b(v1.y); o1.z = f2b(v1.z); o1.w = f2b(v1.w);
            ushort4* dst = (ushort4*)(w1s + u * 8);
            dst[0] = o0; dst[1] = o1;
        }
    }
}

__global__ __launch_bounds__(1024, 4)
void edge_mlp_kernel(const int* __restrict__ ei, const unsigned short* __restrict__ zb,
                     const unsigned short* __restrict__ w1s,
                     const float* __restrict__ b1, const float* __restrict__ W2,
                     const float* __restrict__ b2p, float* __restrict__ out,
                     int E, int ntiles) {
    __shared__ unsigned short ldsA[2][64 * 256];  // 64 KB, dbuf A tiles
    __shared__ float ldsY[16 * 64];               // 4 KB partial-y exchange
    __shared__ float ldsB1[512];                  // 2 KB staged b1
    __shared__ float ldsW2[512];                  // 2 KB staged W2

    const int tid  = threadIdx.x;
    const int lane = tid & 63;
    const int w    = tid >> 6;        // 0..15 : 32-h slice of H=512
    const int l15  = lane & 15;
    const int l4   = lane >> 4;
    const int G    = gridDim.x;
    const int t0   = blockIdx.x;
    if (t0 >= ntiles) return;

    if (tid < 512) {
        ldsB1[tid] = b1[tid];
        ldsW2[tid] = W2[tid];
    }

    // ---- persistent W1: wave w holds hblk w*2..w*2+1, full K, in regs ----
    uint4 breg[2][8];                 // 64 regs
    #pragma unroll
    for (int j = 0; j < 2; ++j)
        #pragma unroll
        for (int kc = 0; kc < 8; ++kc)
            breg[j][kc] = *(const uint4*)(w1s + (((w * 2 + j) * 8 + kc) << 9) + lane * 8);

    const float b2v = b2p[0];

    // gather: instr q covers rows m=(w*4+q*2)+rsub; lane L writes LDS slot
    // L&31 of the row pair; source slot pre-swizzled s15 = l15 ^ (m&7).
    const int side = (lane >> 4) & 1;
    const int rsub = lane >> 5;
    const int swz  = l15 & 7;

#define ISSUE_GATHER(BUF)                                                     \
    do {                                                                      \
        _Pragma("unroll")                                                     \
        for (int q_ = 0; q_ < 2; ++q_) {                                      \
            int m_   = w * 4 + q_ * 2 + rsub;                                 \
            int s15_ = l15 ^ (m_ & 7);                                        \
            gload_lds16(zb + (((long)ival[q_]) << 7) + (s15_ << 3),           \
                        &ldsA[BUF][(w * 4 + q_ * 2) << 8]);                   \
        }                                                                     \
    } while (0)

    asm volatile("s_waitcnt lgkmcnt(0)" ::: "memory");   // ldsB1/ldsW2 writes done

    // ---- prologue: idx(T0) -> gather(T0) -> idx(T1) ----
    int ival[2];
    #pragma unroll
    for (int q = 0; q < 2; ++q) {
        int e = t0 * 64 + w * 4 + q * 2 + rsub;
        e = (e < E) ? e : (E - 1);
        ival[q] = ei[side * E + e];
    }
    ISSUE_GATHER(0);
    asm volatile("" ::: "memory");     // pin: idx(T1) stays AFTER gathers
    {
        int t1 = t0 + G;
        #pragma unroll
        for (int q = 0; q < 2; ++q) {
            int e = t1 * 64 + w * 4 + q * 2 + rsub;
            e = (e < E) ? e : (E - 1);
            ival[q] = ei[side * E + e];
        }
    }

    int cur = 0;
    for (int t = t0; t < ntiles; t += G) {
        // own 2 gathers are the oldest vmem; idx(2) (+store) are newer
        asm volatile("s_waitcnt vmcnt(2)" ::: "memory");
        __builtin_amdgcn_s_barrier();
        asm volatile("" ::: "memory");

        const unsigned short* bufc = &ldsA[cur][0];
        unsigned short* bufn = &ldsA[cur ^ 1][0];

        // acc init = b1 (acc ends as W1.x + b1); C row=h, col=edge
        f32x4 acc[4][2];                  // [edge-tile i][h-tile j]
        {
            f32x4 b1t[2];
            #pragma unroll
            for (int j = 0; j < 2; ++j)
                b1t[j] = *(const f32x4*)&ldsB1[(w * 2 + j) * 16 + l4 * 4];
            #pragma unroll
            for (int i = 0; i < 4; i++)
                #pragma unroll
                for (int j = 0; j < 2; j++) acc[i][j] = b1t[j];
        }

        __builtin_amdgcn_s_setprio(1);
        #pragma unroll
        for (int kc = 0; kc < 4; ++kc) {
            bf16x8 a[4];
            #pragma unroll
            for (int i = 0; i < 4; ++i)
                a[i] = *(const bf16x8*)&bufc[((l15 + 16 * i) << 8) + ((((kc << 2) + l4) ^ swz) << 3)];
            #pragma unroll
            for (int i = 0; i < 4; ++i)
                #pragma unroll
                for (int j = 0; j < 2; ++j)
                    acc[i][j] = __builtin_amdgcn_mfma_f32_16x16x32_bf16(
                        *(const bf16x8*)&breg[j][kc], a[i], acc[i][j], 0, 0, 0);
        }
        __builtin_amdgcn_s_setprio(0);

        // issue next tile's gathers (HBM latency hides under kc4..7)
        ISSUE_GATHER(cur ^ 1);
        asm volatile("" ::: "memory");  // pin: tail idx loads stay AFTER gathers

        __builtin_amdgcn_s_setprio(1);
        #pragma unroll
        for (int kc = 4; kc < 8; ++kc) {
            bf16x8 a[4];
            #pragma unroll
            for (int i = 0; i < 4; ++i)
                a[i] = *(const bf16x8*)&bufc[((l15 + 16 * i) << 8) + ((((kc << 2) + l4) ^ swz) << 3)];
            #pragma unroll
            for (int i = 0; i < 4; ++i)
                #pragma unroll
                for (int j = 0; j < 2; ++j)
                    acc[i][j] = __builtin_amdgcn_mfma_f32_16x16x32_bf16(
                        *(const bf16x8*)&breg[j][kc], a[i], acc[i][j], 0, 0, 0);
        }
        __builtin_amdgcn_s_setprio(0);

        // tail: idx for tile t+2G (consumed by NEXT iter's gather-issue)
        {
            int tt = t + 2 * G;
            #pragma unroll
            for (int q = 0; q < 2; ++q) {
                int e = tt * 64 + w * 4 + q * 2 + rsub;
                e = (e < E) ? e : (E - 1);
                ival[q] = ei[side * E + e];
            }
        }

        // epilogue: y[e] = sum_h relu(acc)*w2; in-reg over (j,r) + 2 shuffles
        {
            f32x4 w2t[2];
            #pragma unroll
            for (int j = 0; j < 2; ++j)
                w2t[j] = *(const f32x4*)&ldsW2[(w * 2 + j) * 16 + l4 * 4];
            #pragma unroll
            for (int i = 0; i < 4; i++) {
                float s = 0.f;
                #pragma unroll
                for (int j = 0; j < 2; j++)
                    #pragma unroll
                    for (int r = 0; r < 4; r++)
                        s = fmaf(fmaxf(acc[i][j][r], 0.f), w2t[j][r], s);
                s += __shfl_xor(s, 16);
                s += __shfl_xor(s, 32);
                if (l4 == 0) ldsY[w * 64 + i * 16 + l15] = s;
            }
        }
        asm volatile("s_waitcnt lgkmcnt(0)" ::: "memory");
        __builtin_amdgcn_s_barrier();
        asm volatile("" ::: "memory");
        if (tid < 64) {
            int e = t * 64 + tid;
            if (e < E) {
                float v = b2v;
                #pragma unroll
                for (int k = 0; k < 16; ++k) v += ldsY[k * 64 + tid];
                out[e] = v;          // single writer; newest vmem in queue
            }
        }

        cur ^= 1;
    }
#undef ISSUE_GATHER
}

extern "C" void kernel_launch(void* const* d_in, const int* in_sizes, int n_in,
                              void* d_out, int out_size, void* d_ws, size_t ws_size,
                              hipStream_t stream) {
    const float* z  = (const float*)d_in[0];
    const int*   ei = (const int*)d_in[1];
    const float* W1 = (const float*)d_in[2];
    const float* b1 = (const float*)d_in[3];
    const float* W2 = (const float*)d_in[4];
    const float* b2 = (const float*)d_in[5];
    float* out = (float*)d_out;

    const int E  = in_sizes[1] / 2;   // 500000
    const int NZ = in_sizes[0];       // 6400000 = N*D

    unsigned short* zb  = (unsigned short*)d_ws;       // 12.8 MB
    unsigned short* w1s = zb + NZ;                     // 256 KB (swizzled W1)

    prep_kernel<<<2048, 256, 0, stream>>>(z, W1, zb, w1s, NZ / 4);

    const int ntiles = (E + 63) / 64;                  // 7813
    int grid = 256;                                    // 1 block/CU, ~31 tiles each
    edge_mlp_kernel<<<grid, 1024, 0, stream>>>(ei, zb, w1s, b1, W2, b2, out, E, ntiles);
}

// Round 6
// 182.793 us; speedup vs baseline: 1.2517x; 1.2517x over previous
//
#include <hip/hip_runtime.h>

// y[e] = W2 . relu(W1 . concat(z[src[e]], z[dst[e]]) + b1) + b2
// N=50000, D=128, H=512, E=500000. 131 GFLOP in GEMM1.
// R13: R10 skeleton + atomic epilogue, single barrier per tile.
// R12 post-mortem: occupancy is NOT the constraint (2x waves -> 0 gain,
// conflicts 2x with 2x LDS read volume). R10's gap (11.8K cyc/tile vs
// ~6-7K overlap floor of MFMA 5.0K | LDS 5.2K) is phase serialization:
// 2 barriers/tile + lgkm drain + wave-0-only store phase.
// Fix: each wave atomicAdds its h-slice partial straight into out[e]
// (8 adds per edge, order-safe; out pre-filled with b2 by prep).
// Removes: ldsY exchange, 2nd barrier, serial store. Keeps: persistent
// blocks (grid=256, 1/CU), W1-in-regs (128/wave), operand-swapped MFMA
// (C row=h col=edge; in-reg h-reduce + 2 shuffles), mid-tile gather issue,
// source-side XOR swizzle, b1 folded into acc init.
// vmcnt ledger (per wave per tile): [4 gathers][4 idx][4 atomics] ->
// newer-than-gathers == 8 at every top-of-tile wait -> s_waitcnt vmcnt(8).
// Prologue issues 4 zero-atomics so the first wait matches. Composition
// only changes on each block's final iteration (masked tail atomics),
// after which no wait depends on it.

typedef __bf16 bf16x8 __attribute__((ext_vector_type(8)));
typedef float f32x4 __attribute__((ext_vector_type(4)));

__device__ __forceinline__ unsigned short f2b(float f) {
    unsigned int u = __float_as_uint(f);
    u = (u + 0x7fffu + ((u >> 16) & 1u)) >> 16;   // RNE
    return (unsigned short)u;
}

__device__ __forceinline__ void gload_lds16(const unsigned short* g, unsigned short* l) {
    __builtin_amdgcn_global_load_lds(
        (const __attribute__((address_space(1))) unsigned int*)g,
        (__attribute__((address_space(3))) unsigned int*)l, 16, 0, 0);
}

// zb: z as bf16 [N][128].  w1s: W1 swizzled to MFMA fragment order:
// w1s[(hblk*8 + kc)*512 + lane*8 + t] = bf16(W1[hblk*16 + (lane&15)][kc*32 + (lane>>4)*8 + t])
// Also pre-fills out[] with b2 (atomicAdd target).
__global__ void prep_kernel(const float* __restrict__ z, const float* __restrict__ W1,
                            const float* __restrict__ b2p,
                            unsigned short* __restrict__ zb, unsigned short* __restrict__ w1s,
                            float* __restrict__ outz, int nz4, int nout4) {
    int stride = gridDim.x * blockDim.x;
    const int nw = 256 * 64;   // (hblk*8+kc) x lane
    const int total = nz4 + nw + nout4;
    const float b2v = b2p[0];
    for (int idx = blockIdx.x * blockDim.x + threadIdx.x; idx < total; idx += stride) {
        if (idx < nz4) {
            float4 v = ((const float4*)z)[idx];
            ushort4 o;
            o.x = f2b(v.x); o.y = f2b(v.y); o.z = f2b(v.z); o.w = f2b(v.w);
            ((ushort4*)zb)[idx] = o;
        } else if (idx < nz4 + nw) {
            int u = idx - nz4;            // 0..16383
            int lane = u & 63;
            int blk  = u >> 6;            // hblk*8 + kc
            int h  = (blk >> 3) * 16 + (lane & 15);
            int kb = (blk & 7) * 32 + (lane >> 4) * 8;
            const float* src = W1 + h * 256 + kb;
            ushort4 o0, o1;
            float4 v0 = *(const float4*)(src);
            float4 v1 = *(const float4*)(src + 4);
            o0.x = f2b(v0.x); o0.y = f2b(v0.y); o0.z = f2b(v0.z); o0.w = f2b(v0.w);
            o1.x = f2b(v1.x); o1.y = f2b(v1.y); o1.z = f2b(v1.z); o1.w = f2b(v1.w);
            ushort4* dst = (ushort4*)(w1s + u * 8);
            dst[0] = o0; dst[1] = o1;
        } else {
            ((float4*)outz)[idx - nz4 - nw] = (float4){b2v, b2v, b2v, b2v};
        }
    }
}

__global__ __launch_bounds__(512, 2)
void edge_mlp_kernel(const int* __restrict__ ei, const unsigned short* __restrict__ zb,
                     const unsigned short* __restrict__ w1s,
                     const float* __restrict__ b1, const float* __restrict__ W2,
                     float* __restrict__ out, int E, int ntiles) {
    __shared__ unsigned short ldsA[2][64 * 256];  // 64 KB, dbuf A tiles
    __shared__ float ldsB1[512];                  // 2 KB staged b1

    const int tid  = threadIdx.x;
    const int lane = tid & 63;
    const int w    = tid >> 6;        // 0..7 : 64-h slice of H=512
    const int l15  = lane & 15;
    const int l4   = lane >> 4;
    const int G    = gridDim.x;
    const int t0   = blockIdx.x;
    if (t0 >= ntiles) return;

    ldsB1[tid] = b1[tid];

    // ---- persistent W1: wave w holds hblk w*4..w*4+3, full K, in regs ----
    uint4 breg[4][8];                 // 128 regs
    #pragma unroll
    for (int j = 0; j < 4; ++j)
        #pragma unroll
        for (int kc = 0; kc < 8; ++kc)
            breg[j][kc] = *(const uint4*)(w1s + (((w * 4 + j) * 8 + kc) << 9) + lane * 8);

    // w2 per lane: h = w*64 + j*16 + l4*4 + r  -> f32x4 per j (16 regs)
    f32x4 w2v[4];
    #pragma unroll
    for (int j = 0; j < 4; ++j)
        w2v[j] = *(const f32x4*)&W2[w * 64 + j * 16 + l4 * 4];

    // gather: instr q covers rows m=(w*8+q*2)+rsub; lane L writes LDS slot
    // L&31 of the row pair; source slot pre-swizzled s15 = l15 ^ (m&7).
    const int side = (lane >> 4) & 1;
    const int rsub = lane >> 5;
    const int swz  = l15 & 7;

#define ISSUE_GATHER(BUF)                                                     \
    do {                                                                      \
        _Pragma("unroll")                                                     \
        for (int q_ = 0; q_ < 4; ++q_) {                                      \
            int m_   = w * 8 + q_ * 2 + rsub;                                 \
            int s15_ = l15 ^ (m_ & 7);                                        \
            gload_lds16(zb + (((long)ival[q_]) << 7) + (s15_ << 3),           \
                        &ldsA[BUF][(w * 8 + q_ * 2) << 8]);                   \
        }                                                                     \
    } while (0)

    // drain staging loads (breg/w2/b1) so the vmcnt ledger starts clean
    asm volatile("s_waitcnt vmcnt(0) lgkmcnt(0)" ::: "memory");

    // ---- prologue: idx(T0) -> gather(T0) -> idx(T1) -> 4 zero-atomics ----
    int ival[4];
    #pragma unroll
    for (int q = 0; q < 4; ++q) {
        int e = t0 * 64 + w * 8 + q * 2 + rsub;
        e = (e < E) ? e : (E - 1);
        ival[q] = ei[side * E + e];
    }
    ISSUE_GATHER(0);
    asm volatile("" ::: "memory");     // pin: idx(T1) stays AFTER gathers
    {
        int t1 = t0 + G;
        #pragma unroll
        for (int q = 0; q < 4; ++q) {
            int e = t1 * 64 + w * 8 + q * 2 + rsub;
            e = (e < E) ? e : (E - 1);
            ival[q] = ei[side * E + e];
        }
    }
    asm volatile("" ::: "memory");     // pin: zero-atomics AFTER idx(T1)
    if (l4 == 0) {                     // 4 queue-padding atomics (add 0.0f)
        #pragma unroll
        for (int i = 0; i < 4; ++i)
            atomicAdd(&out[t0 * 64 + i * 16 + l15], 0.0f);
    }

    int cur = 0;
    for (int t = t0; t < ntiles; t += G) {
        // own 4 gathers are oldest; 4 idx + 4 atomics are newer -> vmcnt(8)
        asm volatile("s_waitcnt vmcnt(8)" ::: "memory");
        __builtin_amdgcn_s_barrier();
        asm volatile("" ::: "memory");

        const unsigned short* bufc = &ldsA[cur][0];

        // acc init = b1 (acc ends as W1.x + b1); C row=h, col=edge
        f32x4 acc[4][4];                  // [edge-tile i][h-tile j]
        {
            f32x4 b1t[4];
            #pragma unroll
            for (int j = 0; j < 4; ++j)
                b1t[j] = *(const f32x4*)&ldsB1[w * 64 + j * 16 + l4 * 4];
            #pragma unroll
            for (int i = 0; i < 4; i++)
                #pragma unroll
                for (int j = 0; j < 4; j++) acc[i][j] = b1t[j];
        }

        __builtin_amdgcn_s_setprio(1);
        #pragma unroll
        for (int kc = 0; kc < 4; ++kc) {
            bf16x8 a[4];
            #pragma unroll
            for (int i = 0; i < 4; ++i)
                a[i] = *(const bf16x8*)&bufc[((l15 + 16 * i) << 8) + ((((kc << 2) + l4) ^ swz) << 3)];
            #pragma unroll
            for (int i = 0; i < 4; ++i)
                #pragma unroll
                for (int j = 0; j < 4; ++j)
                    acc[i][j] = __builtin_amdgcn_mfma_f32_16x16x32_bf16(
                        *(const bf16x8*)&breg[j][kc], a[i], acc[i][j], 0, 0, 0);
        }
        __builtin_amdgcn_s_setprio(0);

        // issue next tile's gathers (HBM latency hides under kc4..7)
        ISSUE_GATHER(cur ^ 1);
        asm volatile("" ::: "memory");

        __builtin_amdgcn_s_setprio(1);
        #pragma unroll
        for (int kc = 4; kc < 8; ++kc) {
            bf16x8 a[4];
            #pragma unroll
            for (int i = 0; i < 4; ++i)
                a[i] = *(const bf16x8*)&bufc[((l15 + 16 * i) << 8) + ((((kc << 2) + l4) ^ swz) << 3)];
            #pragma unroll
            for (int i = 0; i < 4; ++i)
                #pragma unroll
                for (int j = 0; j < 4; ++j)
                    acc[i][j] = __builtin_amdgcn_mfma_f32_16x16x32_bf16(
                        *(const bf16x8*)&breg[j][kc], a[i], acc[i][j], 0, 0, 0);
        }
        __builtin_amdgcn_s_setprio(0);

        // tail: idx for tile t+2G (consumed by NEXT iter's gather-issue)
        {
            int tt = t + 2 * G;
            #pragma unroll
            for (int q = 0; q < 4; ++q) {
                int e = tt * 64 + w * 8 + q * 2 + rsub;
                e = (e < E) ? e : (E - 1);
                ival[q] = ei[side * E + e];
            }
        }
        asm volatile("" ::: "memory");  // pin: epilogue atomics AFTER idx

        // epilogue: y-partial = sum_{h in slice} relu(acc)*w2 ; 2 shuffles;
        // wave adds its partial straight into out[e] (out pre-filled w/ b2)
        float s4[4];
        #pragma unroll
        for (int i = 0; i < 4; i++) {
            float s = 0.f;
            #pragma unroll
            for (int j = 0; j < 4; j++)
                #pragma unroll
                for (int r = 0; r < 4; r++)
                    s = fmaf(fmaxf(acc[i][j][r], 0.f), w2v[j][r], s);
            s += __shfl_xor(s, 16);
            s += __shfl_xor(s, 32);
            s4[i] = s;
        }
        #pragma unroll
        for (int i = 0; i < 4; i++) {
            int e = t * 64 + i * 16 + l15;
            if (l4 == 0 && e < E) atomicAdd(&out[e], s4[i]);
        }

        cur ^= 1;
    }
#undef ISSUE_GATHER
}

extern "C" void kernel_launch(void* const* d_in, const int* in_sizes, int n_in,
                              void* d_out, int out_size, void* d_ws, size_t ws_size,
                              hipStream_t stream) {
    const float* z  = (const float*)d_in[0];
    const int*   ei = (const int*)d_in[1];
    const float* W1 = (const float*)d_in[2];
    const float* b1 = (const float*)d_in[3];
    const float* W2 = (const float*)d_in[4];
    const float* b2 = (const float*)d_in[5];
    float* out = (float*)d_out;

    const int E  = in_sizes[1] / 2;   // 500000
    const int NZ = in_sizes[0];       // 6400000 = N*D

    unsigned short* zb  = (unsigned short*)d_ws;       // 12.8 MB
    unsigned short* w1s = zb + NZ;                     // 256 KB (swizzled W1)

    prep_kernel<<<2048, 256, 0, stream>>>(z, W1, b2, zb, w1s, out, NZ / 4, E / 4);

    const int ntiles = (E + 63) / 64;                  // 7813
    int grid = 256;                                    // persistent, 1 block/CU
    edge_mlp_kernel<<<grid, 512, 0, stream>>>(ei, zb, w1s, b1, W2, out, E, ntiles);
}